// Round 5
// baseline (452.954 us; speedup 1.0000x reference)
//
#include <hip/hip_runtime.h>
#include <hip/hip_cooperative_groups.h>

namespace cg = cooperative_groups;

typedef unsigned int u32;
typedef unsigned long long u64;

#define NCLS 80
#define NTOT 3000
#define CAND_CAP 4096

// ---- workspace layout (bytes) ----
#define WS_HIST      0        // 3*256*4 = 3072
#define WS_CNT       3072     // 3*4
#define WS_CAND      4096     // 3*4096*8
#define WS_SEL       102400   // 3000*8
#define WS_OFFBOX    138400   // 3000*4*4
#define WS_VALID     186400   // 3000*4
#define WS_LABEL     198400   // 3000*4

// hist bins: p in [0.5,1.0), bin = (pb>>15) - 0x7E00, 2^15-ulp wide, 256 bins.
#define PB_HALF 0x3F000000u
#define PB_QUARTER 0x3E800000u

__device__ __forceinline__ float sigm(float x) {
#pragma clang fp contract(off)
    return 1.0f / (1.0f + expf(-x));
}

// map block -> (level, anchor base). 400 + 100 + 25 = 525 blocks of 256 anchors.
__device__ __forceinline__ void block_map(int b, int& L, int& m0) {
    if (b < 400)      { L = 0; m0 = b * 256; }
    else if (b < 500) { L = 1; m0 = (b - 400) * 256; }
    else              { L = 2; m0 = (b - 500) * 256; }
}

// One cooperative kernel, 525 blocks x 256 threads, 32 KB LDS reused per phase.
// Phases: P0 zero ws | P1 hist | P2 filter | P3 rank-select | P4 merge+decode | P5 NMS
__global__ __launch_bounds__(256) void fused_kernel(
    const float* __restrict__ o0, const float* __restrict__ c0, const float* __restrict__ r0,
    const float* __restrict__ o1, const float* __restrict__ c1, const float* __restrict__ r1,
    const float* __restrict__ o2, const float* __restrict__ c2, const float* __restrict__ r2,
    float* __restrict__ out,
    u32* __restrict__ whist, u32* __restrict__ wcnt, u64* __restrict__ wcand,
    u64* __restrict__ wsel, float* __restrict__ woffb,
    u32* __restrict__ wvalid, u32* __restrict__ wlabel) {
#pragma clang fp contract(off)
    __shared__ u64 smem64[CAND_CAP];  // 32 KB, re-cast per phase
    cg::grid_group grid = cg::this_grid();
    int tid = threadIdx.x;
    int b = (int)blockIdx.x;
    int L, m0; block_map(b, L, m0);
    const float* obj = (L == 0) ? o0 : ((L == 1) ? o1 : o2);
    const float* cls = (L == 0) ? c0 : ((L == 1) ? c1 : c2);
    const float4* cls4 = (const float4*)cls;

    // ---- P0: zero hist + cnt (d_ws is poisoned 0xAA each call) ----
    if (b == 0) {
        for (int i = tid; i < 768; i += 256) whist[i] = 0u;
        if (tid < 3) wcnt[tid] = 0u;
    }
    grid.sync();

    // ---- P1: histogram of p = sig(obj)*sig(cls) over [0.5,1) ----
    {
        u32* h = (u32*)smem64;                 // [8][257] = 8224 B
        u32* alist = h + 8 * 257;              // 256
        float* slist = (float*)(alist + 256);  // 256
        u32* nshp = (u32*)(slist + 256);
        for (int k = tid; k < 8 * 257; k += 256) h[k] = 0u;
        if (tid == 0) *nshp = 0u;
        __syncthreads();
        float so = sigm(obj[m0 + tid]);
        bool pass = __float_as_uint(so) >= PB_HALF;  // p <= so
        u64 mask = __ballot(pass);
        u32 lane = (u32)(tid & 63);
        u32 pc = (u32)__popcll(mask);
        u32 wbase = 0;
        if (lane == 0 && pc) wbase = atomicAdd(nshp, pc);
        wbase = (u32)__shfl((int)wbase, 0);
        if (pass) {
            u32 off = (u32)__popcll(mask & ((1ull << lane) - 1ull));
            alist[wbase + off] = (u32)tid;
            slist[wbase + off] = so;
        }
        __syncthreads();
        int n = (int)*nshp;
        u32 rep = (u32)(tid & 7);
        for (int i = tid; i < n * 20; i += 256) {
            int j = i / 20, k = i - j * 20;
            int a = m0 + (int)alist[j];
            float soj = slist[j];
            float4 v = cls4[a * 20 + k];
            float vv[4] = {v.x, v.y, v.z, v.w};
#pragma unroll
            for (int q = 0; q < 4; ++q) {
                float p = soj * sigm(vv[q]);
                u32 pb = __float_as_uint(p);
                if (pb >= PB_HALF) {
                    u32 bin = min((pb >> 15) - 0x7E00u, 255u);
                    atomicAdd(&h[rep * 257 + bin], 1u);
                }
            }
        }
        __syncthreads();
        if (tid < 256) {
            u32 s = 0;
            for (int r = 0; r < 8; ++r) s += h[r * 257 + tid];
            if (s) atomicAdd(&whist[L * 256 + tid], s);
        }
    }
    grid.sync();

    // ---- P2: filter — inline cutoff (suffix scan), row-skip, emit candidates ----
    {
        u32* sh = (u32*)smem64;               // 256
        int* cutbin = (int*)(sh + 256);
        u32* thrsh = (u32*)(cutbin + 1);
        u32* alist = thrsh + 1;               // 256
        float* slist = (float*)(alist + 256); // 256
        u32* nshp = (u32*)(slist + 256);
        if (tid == 0) { *cutbin = -1; *nshp = 0u; }
        sh[tid] = whist[L * 256 + tid];
        __syncthreads();
        for (int off = 1; off < 256; off <<= 1) {
            u32 v = (tid + off < 256) ? sh[tid + off] : 0u;
            __syncthreads();
            sh[tid] += v;
            __syncthreads();
        }
        if (sh[tid] >= 1000u) atomicMax(cutbin, tid);
        __syncthreads();
        if (tid == 0) {
            // one-bin margin below the rank-1000 bin covers sqrt-tie hazards
            *thrsh = (*cutbin >= 0) ? (PB_HALF + ((u32)*cutbin << 15)) - 0x8000u
                                    : PB_QUARTER;
        }
        __syncthreads();
        u32 thr = *thrsh;
        float so = sigm(obj[m0 + tid]);
        bool pass = __float_as_uint(so) >= thr;  // p <= so
        u64 mask = __ballot(pass);
        u32 lane = (u32)(tid & 63);
        u32 pc = (u32)__popcll(mask);
        u32 wbase = 0;
        if (lane == 0 && pc) wbase = atomicAdd(nshp, pc);
        wbase = (u32)__shfl((int)wbase, 0);
        if (pass) {
            u32 off = (u32)__popcll(mask & ((1ull << lane) - 1ull));
            alist[wbase + off] = (u32)tid;
            slist[wbase + off] = so;
        }
        __syncthreads();
        int n = (int)*nshp;
        for (int i = tid; i < n * 20; i += 256) {
            int j = i / 20, k = i - j * 20;
            int a = m0 + (int)alist[j];
            float soj = slist[j];
            float4 v = cls4[a * 20 + k];
            float vv[4] = {v.x, v.y, v.z, v.w};
#pragma unroll
            for (int q = 0; q < 4; ++q) {
                float p = soj * sigm(vv[q]);
                u32 pb = __float_as_uint(p);
                if (pb >= thr) {
                    float s = sqrtf(p);
                    u32 sb = __float_as_uint(s);
                    u32 slot = atomicAdd(&wcnt[L], 1u);
                    if (slot < CAND_CAP) {
                        u32 idx = (u32)(a * NCLS + (k * 4 + q));
                        wcand[L * CAND_CAP + slot] = ((u64)(sb ^ 0xFFFFFFFFu) << 32) | idx;
                    }
                }
            }
        }
    }
    grid.sync();

    // ---- P3: exact top-1000 per level by rank-counting (keys unique) ----
    if (b < 48) {
        u64* s = smem64;
        int RL = b >> 4, part = b & 15;
        int n = (int)min(wcnt[RL], (u32)CAND_CAP);
        if (part * 256 < n) {
            for (int j = tid; j < n; j += 256) s[j] = wcand[RL * CAND_CAP + j];
            __syncthreads();
            int i = part * 256 + tid;
            if (i < n) {
                u64 mykey = s[i];
                int rank = 0;
#pragma unroll 4
                for (int j = 0; j < n; ++j) rank += (s[j] < mykey);
                if (rank < 1000) wsel[RL * 1000 + rank] = mykey;
            }
        }
    }
    grid.sync();

    // ---- P4: merge (LDS binary searches) + decode + write outputs ----
    if (b < 3) {
        u64* k = smem64;  // 3000 u64
        for (int i = tid; i < NTOT; i += 256)
            k[i] = (wsel[i] & 0xFFFFFFFF00000000ull) | (u32)i;
        __syncthreads();
        int ML = b;
        int w = (ML == 0) ? 320 : ((ML == 1) ? 160 : 80);
        float st = (ML == 0) ? 8.0f : ((ML == 1) ? 16.0f : 32.0f);
        const float* reg = (ML == 0) ? r0 : ((ML == 1) ? r1 : r2);
        for (int rr = tid; rr < 1000; rr += 256) {
            int t = ML * 1000 + rr;
            u64 key = k[t];
            int g = rr;
            for (int O = 0; O < 3; ++O) {
                if (O == ML) continue;
                int lo = 0, hi = 1000;
                while (lo < hi) {
                    int mid = (lo + hi) >> 1;
                    if (k[O * 1000 + mid] < key) lo = mid + 1; else hi = mid;
                }
                g += lo;
            }
            u64 S = wsel[t];
            u32 bits = (u32)(S >> 32) ^ 0xFFFFFFFFu;
            u32 idx = (u32)S;
            float score = __uint_as_float(bits);
            int label = (int)(idx % NCLS);
            int m = (int)(idx / NCLS);
            int x = m % w, y = m / w;
            float rv0 = reg[m * 4 + 0], rv1 = reg[m * 4 + 1];
            float rv2 = reg[m * 4 + 2], rv3 = reg[m * 4 + 3];
            float ax = ((float)x + 0.5f) * st;
            float ay = ((float)y + 0.5f) * st;
            float cx = ax + rv0 * st;
            float cy = ay + rv1 * st;
            float bw = expf(rv2) * st;
            float bh = expf(rv3) * st;
            float hx = 0.5f * bw, hy = 0.5f * bh;
            float x1 = cx - hx, y1 = cy - hy, x2 = cx + hx, y2 = cy + hy;
            out[g * 4 + 0] = x1; out[g * 4 + 1] = y1;
            out[g * 4 + 2] = x2; out[g * 4 + 3] = y2;
            out[12000 + g] = score;
            out[15000 + g] = (float)label;
            float off = (float)label * 8192.0f;
            woffb[g * 4 + 0] = x1 + off; woffb[g * 4 + 1] = y1 + off;
            woffb[g * 4 + 2] = x2 + off; woffb[g * 4 + 3] = y2 + off;
            wvalid[g] = (score > 0.05f) ? 1u : 0u;
            wlabel[g] = (u32)label;
        }
    }
    grid.sync();

    // ---- P5: per-class greedy NMS (1 wave per class; cross-class IoU == 0) ----
    if (b < 80 && tid < 64) {
        float* bx = (float*)smem64;       // 1024*4 floats
        u32* lg = (u32*)(bx + 4096);      // 1024
        int c = b, lane = tid;
        float* keep_out = out + 18000;
        u32 cnt = 0;
        for (int chunk = 0; chunk < 47; ++chunk) {
            int g = chunk * 64 + lane;
            bool match = (g < NTOT) && (wlabel[g] == (u32)c);
            u64 mask = __ballot(match);
            u32 off = (u32)__popcll(mask & ((1ull << lane) - 1ull));
            u32 p = cnt + off;
            if (match && p < 1024) {
                lg[p] = (u32)g;
                bx[p * 4 + 0] = woffb[g * 4 + 0];
                bx[p * 4 + 1] = woffb[g * 4 + 1];
                bx[p * 4 + 2] = woffb[g * 4 + 2];
                bx[p * 4 + 3] = woffb[g * 4 + 3];
            }
            cnt += (u32)__popcll(mask);
        }
        int n = (int)min(cnt, 1024u);
        int K = (n + 63) >> 6;
        u32 alive = 0;
        for (int k = 0; k < K; ++k) {
            int p = lane + (k << 6);
            if (p < n && wvalid[lg[p]]) alive |= (1u << k);
        }
        for (int a = 0; a < n; ++a) {
            u32 owner = __shfl(alive, a & 63);
            if ((owner >> (a >> 6)) & 1u) {
                float a0 = bx[a * 4 + 0], a1 = bx[a * 4 + 1];
                float a2 = bx[a * 4 + 2], a3 = bx[a * 4 + 3];
                float areaA = (a2 - a0) * (a3 - a1);
                for (int k = (a >> 6); k < K; ++k) {
                    int p = lane + (k << 6);
                    if (p > a && p < n && ((alive >> k) & 1u)) {
                        float b0 = bx[p * 4 + 0], b1 = bx[p * 4 + 1];
                        float b2 = bx[p * 4 + 2], b3 = bx[p * 4 + 3];
                        float areaB = (b2 - b0) * (b3 - b1);
                        float ltx = fmaxf(a0, b0), lty = fmaxf(a1, b1);
                        float rbx = fminf(a2, b2), rby = fminf(a3, b3);
                        float wx = fmaxf(rbx - ltx, 0.0f), wy = fmaxf(rby - lty, 0.0f);
                        float inter = wx * wy;
                        float denom = ((areaA + areaB) - inter) + 1e-9f;
                        float iou = inter / denom;
                        if (iou > 0.6f) alive &= ~(1u << k);
                    }
                }
            }
        }
        for (int k = 0; k < K; ++k) {
            int p = lane + (k << 6);
            if (p < n) keep_out[lg[p]] = ((alive >> k) & 1u) ? 1.0f : 0.0f;
        }
    }
}

extern "C" void kernel_launch(void* const* d_in, const int* in_sizes, int n_in,
                              void* d_out, int out_size, void* d_ws, size_t ws_size,
                              hipStream_t stream) {
    const float* obj0 = (const float*)d_in[0];
    const float* cls0 = (const float*)d_in[1];
    const float* reg0 = (const float*)d_in[2];
    const float* obj1 = (const float*)d_in[3];
    const float* cls1 = (const float*)d_in[4];
    const float* reg1 = (const float*)d_in[5];
    const float* obj2 = (const float*)d_in[6];
    const float* cls2 = (const float*)d_in[7];
    const float* reg2 = (const float*)d_in[8];
    float* out = (float*)d_out;
    char* ws = (char*)d_ws;

    u32* hist   = (u32*)(ws + WS_HIST);
    u32* cnt    = (u32*)(ws + WS_CNT);
    u64* cand   = (u64*)(ws + WS_CAND);
    u64* sel    = (u64*)(ws + WS_SEL);
    float* offb = (float*)(ws + WS_OFFBOX);
    u32* valid  = (u32*)(ws + WS_VALID);
    u32* labelu = (u32*)(ws + WS_LABEL);

    void* args[] = {
        (void*)&obj0, (void*)&cls0, (void*)&reg0,
        (void*)&obj1, (void*)&cls1, (void*)&reg1,
        (void*)&obj2, (void*)&cls2, (void*)&reg2,
        (void*)&out,
        (void*)&hist, (void*)&cnt, (void*)&cand,
        (void*)&sel, (void*)&offb, (void*)&valid, (void*)&labelu
    };
    hipLaunchCooperativeKernel((const void*)fused_kernel, dim3(525), dim3(256),
                               args, 0, stream);
}

// Round 6
// 240.586 us; speedup vs baseline: 1.8827x; 1.8827x over previous
//
#include <hip/hip_runtime.h>

typedef unsigned int u32;
typedef unsigned long long u64;

#define NCLS 80
#define NTOT 3000
#define CAND_CAP 4096
#define NBLK 525

// ---- workspace layout (bytes); first 4096 zeroed by memsetAsync ----
#define WS_HIST   0       // 768 u32
#define WS_CNT    3072    // 3 u32
#define WS_DONEA  3084    // u32
#define WS_DONEB  3088    // u32
#define WS_DONEC  3092    // u32
#define WS_CAND   4096    // 3*4096 u64
#define WS_SEL    102400  // 3000 u64

// hist bins: p in [0.5,1.0), bin = (pb>>15) - 0x7E00, 256 bins.
#define PB_HALF    0x3F000000u
#define PB_QUARTER 0x3E800000u

__device__ __forceinline__ float sigm(float x) {
#pragma clang fp contract(off)
    return 1.0f / (1.0f + expf(-x));
}

// coherent-point accessors (device-scope atomics bypass the non-coherent L2s)
__device__ __forceinline__ u32 aload32(u32* p) { return atomicAdd(p, 0u); }
__device__ __forceinline__ u64 aload64(u64* p) { return atomicAdd(p, 0ull); }

__device__ __forceinline__ void spin_until(u32* flag, u32 target) {
    for (int it = 0; it < (1 << 22); ++it) {  // bailout ~0.2 s, prevents hangs
        if (atomicAdd(flag, 0u) >= target) return;
        __builtin_amdgcn_s_sleep(2);
    }
}

__device__ __forceinline__ void block_map(int b, int& L, int& m0) {
    if (b < 400)      { L = 0; m0 = b * 256; }
    else if (b < 500) { L = 1; m0 = (b - 400) * 256; }
    else              { L = 2; m0 = (b - 500) * 256; }
}

// single kernel, 525 blocks x 256 threads; phases glued by atomic flag barriers.
__global__ __launch_bounds__(256) void fused_kernel(
    const float* __restrict__ o0, const float* __restrict__ c0, const float* __restrict__ r0,
    const float* __restrict__ o1, const float* __restrict__ c1, const float* __restrict__ r1,
    const float* __restrict__ o2, const float* __restrict__ c2, const float* __restrict__ r2,
    float* __restrict__ out,
    u32* __restrict__ whist, u32* __restrict__ wcnt,
    u32* __restrict__ doneA, u32* __restrict__ doneB, u32* __restrict__ doneC,
    u64* __restrict__ wcand, u64* __restrict__ wsel) {
#pragma clang fp contract(off)
    __shared__ u64 smem64[4096];  // 32 KB, re-cast per phase
    int tid = threadIdx.x;
    int b = (int)blockIdx.x;
    int L, m0; block_map(b, L, m0);
    const float* obj = (L == 0) ? o0 : ((L == 1) ? o1 : o2);
    const float* cls = (L == 0) ? c0 : ((L == 1) ? c1 : c2);
    const float4* cls4 = (const float4*)cls;

    // ================= PHASE A: histogram =================
    {
        u32* h = (u32*)smem64;                 // 8*257
        u32* alist = h + 8 * 257;              // 256
        float* slist = (float*)(alist + 256);  // 256
        u32* nshp = (u32*)(slist + 256);
        for (int k = tid; k < 8 * 257; k += 256) h[k] = 0u;
        if (tid == 0) *nshp = 0u;
        __syncthreads();
        float so = sigm(obj[m0 + tid]);
        bool pass = __float_as_uint(so) >= PB_HALF;  // p <= so
        u64 mask = __ballot(pass);
        u32 lane = (u32)(tid & 63);
        u32 pc = (u32)__popcll(mask);
        u32 wbase = 0;
        if (lane == 0 && pc) wbase = atomicAdd(nshp, pc);
        wbase = (u32)__shfl((int)wbase, 0);
        if (pass) {
            u32 off = (u32)__popcll(mask & ((1ull << lane) - 1ull));
            alist[wbase + off] = (u32)tid;
            slist[wbase + off] = so;
        }
        __syncthreads();
        int n = (int)*nshp;
        u32 rep = (u32)(tid & 7);
        for (int i = tid; i < n * 20; i += 256) {
            int j = i / 20, k = i - j * 20;
            int a = m0 + (int)alist[j];
            float soj = slist[j];
            float4 v = cls4[a * 20 + k];
            float vv[4] = {v.x, v.y, v.z, v.w};
#pragma unroll
            for (int q = 0; q < 4; ++q) {
                float p = soj * sigm(vv[q]);
                u32 pb = __float_as_uint(p);
                if (pb >= PB_HALF) {
                    u32 bin = min((pb >> 15) - 0x7E00u, 255u);
                    atomicAdd(&h[rep * 257 + bin], 1u);
                }
            }
        }
        __syncthreads();
        if (tid < 256) {
            u32 s = 0;
            for (int r = 0; r < 8; ++r) s += h[r * 257 + tid];
            if (s) atomicAdd(&whist[L * 256 + tid], s);  // device-scope, coherent
        }
    }
    __syncthreads();  // drains vmcnt: all this block's atomics retired
    if (tid == 0) atomicAdd(doneA, 1u);
    // -------- full barrier: wait for all 525 hist contributions --------
    if (tid == 0) spin_until(doneA, NBLK);
    __syncthreads();

    // ================= PHASE B: filter =================
    {
        u32* sh = (u32*)smem64;               // 256
        u32* alist = sh + 256;                // 256
        float* slist = (float*)(alist + 256); // 256
        int* cutbin = (int*)(slist + 256);
        u32* thrsh = (u32*)(cutbin + 1);
        u32* nshp = thrsh + 1;
        if (tid == 0) { *cutbin = -1; *nshp = 0u; }
        sh[tid] = aload32(&whist[L * 256 + tid]);
        __syncthreads();
        for (int off = 1; off < 256; off <<= 1) {
            u32 v = (tid + off < 256) ? sh[tid + off] : 0u;
            __syncthreads();
            sh[tid] += v;
            __syncthreads();
        }
        if (sh[tid] >= 1000u) atomicMax(cutbin, tid);
        __syncthreads();
        if (tid == 0) {
            // one-bin margin below the rank-1000 bin covers sqrt-tie hazards
            *thrsh = (*cutbin >= 0) ? (PB_HALF + ((u32)*cutbin << 15)) - 0x8000u
                                    : PB_QUARTER;
        }
        __syncthreads();
        u32 thr = *thrsh;
        float so = sigm(obj[m0 + tid]);
        bool pass = __float_as_uint(so) >= thr;  // p <= so
        u64 mask = __ballot(pass);
        u32 lane = (u32)(tid & 63);
        u32 pc = (u32)__popcll(mask);
        u32 wbase = 0;
        if (lane == 0 && pc) wbase = atomicAdd(nshp, pc);
        wbase = (u32)__shfl((int)wbase, 0);
        if (pass) {
            u32 off = (u32)__popcll(mask & ((1ull << lane) - 1ull));
            alist[wbase + off] = (u32)tid;
            slist[wbase + off] = so;
        }
        __syncthreads();
        int n = (int)*nshp;
        for (int i = tid; i < n * 20; i += 256) {
            int j = i / 20, k = i - j * 20;
            int a = m0 + (int)alist[j];
            float soj = slist[j];
            float4 v = cls4[a * 20 + k];
            float vv[4] = {v.x, v.y, v.z, v.w};
#pragma unroll
            for (int q = 0; q < 4; ++q) {
                float p = soj * sigm(vv[q]);
                u32 pb = __float_as_uint(p);
                if (pb >= thr) {
                    float s = sqrtf(p);
                    u32 sb = __float_as_uint(s);
                    u32 slot = atomicAdd(&wcnt[L], 1u);
                    if (slot < CAND_CAP) {
                        u32 idx = (u32)(a * NCLS + (k * 4 + q));
                        atomicExch(&wcand[L * CAND_CAP + slot],
                                   ((u64)(sb ^ 0xFFFFFFFFu) << 32) | idx);
                    }
                }
            }
        }
    }
    __syncthreads();  // drain
    if (tid == 0) atomicAdd(doneB, 1u);

    // ================= PHASE C: rank-select (blocks 0..47) =================
    if (b < 48) {
        if (tid == 0) spin_until(doneB, NBLK);
        __syncthreads();
        u64* s = smem64;
        int RL = b >> 4, part = b & 15;
        int n = (int)min(aload32(&wcnt[RL]), (u32)CAND_CAP);
        if (part * 256 < n) {
            for (int j = tid; j < n; j += 256) s[j] = aload64(&wcand[RL * CAND_CAP + j]);
            __syncthreads();
            int i = part * 256 + tid;
            if (i < n) {
                u64 mykey = s[i];
                int rank = 0;
#pragma unroll 4
                for (int j = 0; j < n; ++j) rank += (s[j] < mykey);  // uniform j: LDS broadcast
                if (rank < 1000) atomicExch(&wsel[RL * 1000 + rank], mykey);
            }
        }
        __syncthreads();  // drain
        if (tid == 0) atomicAdd(doneC, 1u);
        return;
    }

    // ================= PHASE D: merge + decode + NMS (blocks 48..127) =====
    if (b >= 128) return;
    {
        int c = b - 48;  // class id
        u64* k = smem64;                       // 3000 keys (tiebreak form)
        u64* ckey = smem64 + 3000;             // 256 class keys
        u32* cidx = (u32*)(smem64 + 3256);     // 256 original idx
        u32* garr = (u32*)(smem64 + 3320);     // 256 global ranks
        u32* invp = (u32*)(smem64 + 3384);     // 256 order->raw
        float* bx = (float*)(smem64 + 3448);   // 256*4 offset boxes
        u32* ncp = (u32*)(smem64 + 3960);
        if (tid == 0) {
            *ncp = 0u;
            spin_until(doneC, 48);
        }
        __syncthreads();
        for (int i = tid; i < NTOT; i += 256) {
            u64 S = aload64(&wsel[i]);
            k[i] = (S & 0xFFFFFFFF00000000ull) | (u32)i;
            u32 idx = (u32)S;
            if ((int)(idx % NCLS) == c) {
                u32 p = atomicAdd(ncp, 1u);
                if (p < 256) {
                    ckey[p] = (S & 0xFFFFFFFF00000000ull) | (u32)i;
                    cidx[p] = idx;
                }
            }
        }
        __syncthreads();
        int nc = (int)min(*ncp, 256u);
        // order within class by (score desc, concat pos asc)
        if (tid < nc) {
            u64 me = ckey[tid];
            int r = 0;
            for (int j = 0; j < nc; ++j) r += (ckey[j] < me);
            invp[r] = (u32)tid;
        }
        // global rank + decode + write boxes/scores/labels
        if (tid < nc) {
            u64 key = ckey[tid];
            int t = (int)(u32)key;
            int ML = t / 1000, rr = t - ML * 1000;
            int g = rr;
            for (int O = 0; O < 3; ++O) {
                if (O == ML) continue;
                int lo = 0, hi = 1000;
                while (lo < hi) {
                    int mid = (lo + hi) >> 1;
                    if (k[O * 1000 + mid] < key) lo = mid + 1; else hi = mid;
                }
                g += lo;
            }
            garr[tid] = (u32)g;
            u32 bits = (u32)(key >> 32) ^ 0xFFFFFFFFu;
            float score = __uint_as_float(bits);
            u32 idx = cidx[tid];
            int m = (int)(idx / NCLS);
            int w = (ML == 0) ? 320 : ((ML == 1) ? 160 : 80);
            float st = (ML == 0) ? 8.0f : ((ML == 1) ? 16.0f : 32.0f);
            const float* reg = (ML == 0) ? r0 : ((ML == 1) ? r1 : r2);
            int x = m % w, y = m / w;
            float rv0 = reg[m * 4 + 0], rv1 = reg[m * 4 + 1];
            float rv2 = reg[m * 4 + 2], rv3 = reg[m * 4 + 3];
            float ax = ((float)x + 0.5f) * st;
            float ay = ((float)y + 0.5f) * st;
            float cx = ax + rv0 * st;
            float cy = ay + rv1 * st;
            float bw = expf(rv2) * st;
            float bh = expf(rv3) * st;
            float hx = 0.5f * bw, hy = 0.5f * bh;
            float x1 = cx - hx, y1 = cy - hy, x2 = cx + hx, y2 = cy + hy;
            out[g * 4 + 0] = x1; out[g * 4 + 1] = y1;
            out[g * 4 + 2] = x2; out[g * 4 + 3] = y2;
            out[12000 + g] = score;
            out[15000 + g] = (float)c;
            float off = (float)c * 8192.0f;
            bx[tid * 4 + 0] = x1 + off; bx[tid * 4 + 1] = y1 + off;
            bx[tid * 4 + 2] = x2 + off; bx[tid * 4 + 3] = y2 + off;
        }
        __syncthreads();
        // greedy NMS in score order, 1 wave
        if (tid < 64) {
            int K = (nc + 63) >> 6;
            u32 alive = 0;
            for (int kk = 0; kk < K; ++kk) {
                int p = tid + (kk << 6);
                if (p < nc) {
                    u32 bits = (u32)(ckey[invp[p]] >> 32) ^ 0xFFFFFFFFu;
                    if (__uint_as_float(bits) > 0.05f) alive |= (1u << kk);
                }
            }
            for (int a = 0; a < nc; ++a) {
                u32 owner = (u32)__shfl((int)alive, a & 63);
                if ((owner >> (a >> 6)) & 1u) {
                    int ra = (int)invp[a];
                    float a0 = bx[ra * 4 + 0], a1 = bx[ra * 4 + 1];
                    float a2 = bx[ra * 4 + 2], a3 = bx[ra * 4 + 3];
                    float areaA = (a2 - a0) * (a3 - a1);
                    for (int kk = (a >> 6); kk < K; ++kk) {
                        int p = tid + (kk << 6);
                        if (p > a && p < nc && ((alive >> kk) & 1u)) {
                            int rp = (int)invp[p];
                            float b0 = bx[rp * 4 + 0], b1 = bx[rp * 4 + 1];
                            float b2 = bx[rp * 4 + 2], b3 = bx[rp * 4 + 3];
                            float areaB = (b2 - b0) * (b3 - b1);
                            float ltx = fmaxf(a0, b0), lty = fmaxf(a1, b1);
                            float rbx = fminf(a2, b2), rby = fminf(a3, b3);
                            float wx = fmaxf(rbx - ltx, 0.0f), wy = fmaxf(rby - lty, 0.0f);
                            float inter = wx * wy;
                            float denom = ((areaA + areaB) - inter) + 1e-9f;
                            float iou = inter / denom;
                            if (iou > 0.6f) alive &= ~(1u << kk);
                        }
                    }
                }
            }
            for (int kk = 0; kk < K; ++kk) {
                int p = tid + (kk << 6);
                if (p < nc)
                    out[18000 + garr[invp[p]]] = ((alive >> kk) & 1u) ? 1.0f : 0.0f;
            }
        }
    }
}

extern "C" void kernel_launch(void* const* d_in, const int* in_sizes, int n_in,
                              void* d_out, int out_size, void* d_ws, size_t ws_size,
                              hipStream_t stream) {
    const float* obj0 = (const float*)d_in[0];
    const float* cls0 = (const float*)d_in[1];
    const float* reg0 = (const float*)d_in[2];
    const float* obj1 = (const float*)d_in[3];
    const float* cls1 = (const float*)d_in[4];
    const float* reg1 = (const float*)d_in[5];
    const float* obj2 = (const float*)d_in[6];
    const float* cls2 = (const float*)d_in[7];
    const float* reg2 = (const float*)d_in[8];
    float* out = (float*)d_out;
    char* ws = (char*)d_ws;

    u32* hist  = (u32*)(ws + WS_HIST);
    u32* cnt   = (u32*)(ws + WS_CNT);
    u32* doneA = (u32*)(ws + WS_DONEA);
    u32* doneB = (u32*)(ws + WS_DONEB);
    u32* doneC = (u32*)(ws + WS_DONEC);
    u64* cand  = (u64*)(ws + WS_CAND);
    u64* sel   = (u64*)(ws + WS_SEL);

    hipMemsetAsync(ws, 0, 4096, stream);  // hist + cnt + flags
    fused_kernel<<<NBLK, 256, 0, stream>>>(obj0, cls0, reg0, obj1, cls1, reg1,
                                           obj2, cls2, reg2, out,
                                           hist, cnt, doneA, doneB, doneC,
                                           cand, sel);
}

// Round 7
// 234.979 us; speedup vs baseline: 1.9276x; 1.0239x over previous
//
#include <hip/hip_runtime.h>

typedef unsigned int u32;
typedef unsigned long long u64;

#define NCLS 80
#define NTOT 3000
#define CAND_CAP 4096
#define NBLK 525

// ---- workspace layout (bytes); first 4096 zeroed by memsetAsync ----
#define WS_HIST   0       // 768 u32
#define WS_CNT    3072    // 3 u32
#define WS_DONEA  3200    // u32 (own cache line)
#define WS_DONEB  3328    // u32
#define WS_DONEC  3456    // u32
#define WS_CAND   4096    // 3*4096 u64
#define WS_SEL    102400  // 3000 u64

// hist bins: p in [0.5,1.0), bin = (pb>>15) - 0x7E00, 256 bins.
#define PB_HALF    0x3F000000u
#define PB_QUARTER 0x3E800000u

__device__ __forceinline__ float sigm(float x) {
#pragma clang fp contract(off)
    return 1.0f / (1.0f + expf(-x));
}

// coherent accessors: plain loads/stores with agent-scope coherence bits
// (bypass non-coherent L1/L2; serviced at LLC; pipelined, NO RMW serialization)
__device__ __forceinline__ u32 cload32(const u32* p) {
    return __hip_atomic_load(p, __ATOMIC_RELAXED, __HIP_MEMORY_SCOPE_AGENT);
}
__device__ __forceinline__ u64 cload64(const u64* p) {
    return __hip_atomic_load(p, __ATOMIC_RELAXED, __HIP_MEMORY_SCOPE_AGENT);
}
__device__ __forceinline__ void cstore64(u64* p, u64 v) {
    __hip_atomic_store(p, v, __ATOMIC_RELAXED, __HIP_MEMORY_SCOPE_AGENT);
}
__device__ __forceinline__ void arrive(u32* flag) {
    __hip_atomic_fetch_add(flag, 1u, __ATOMIC_RELEASE, __HIP_MEMORY_SCOPE_AGENT);
}
__device__ __forceinline__ void wait_for(u32* flag, u32 target) {
    int it = 0;
    while (__hip_atomic_load(flag, __ATOMIC_RELAXED, __HIP_MEMORY_SCOPE_AGENT) < target
           && it++ < (1 << 24)) {
        __builtin_amdgcn_s_sleep(8);
    }
    (void)__hip_atomic_load(flag, __ATOMIC_ACQUIRE, __HIP_MEMORY_SCOPE_AGENT);
}

__device__ __forceinline__ void block_map(int b, int& L, int& m0) {
    if (b < 400)      { L = 0; m0 = b * 256; }
    else if (b < 500) { L = 1; m0 = (b - 400) * 256; }
    else              { L = 2; m0 = (b - 500) * 256; }
}

// single kernel, 525 blocks x 256 threads; phases glued by flag barriers.
__global__ __launch_bounds__(256) void fused_kernel(
    const float* __restrict__ o0, const float* __restrict__ c0, const float* __restrict__ r0,
    const float* __restrict__ o1, const float* __restrict__ c1, const float* __restrict__ r1,
    const float* __restrict__ o2, const float* __restrict__ c2, const float* __restrict__ r2,
    float* __restrict__ out,
    u32* __restrict__ whist, u32* __restrict__ wcnt,
    u32* __restrict__ doneA, u32* __restrict__ doneB, u32* __restrict__ doneC,
    u64* __restrict__ wcand, u64* __restrict__ wsel) {
#pragma clang fp contract(off)
    __shared__ u64 smem64[4096];  // 32 KB, re-cast per phase
    int tid = threadIdx.x;
    int b = (int)blockIdx.x;
    u32 lane = (u32)(tid & 63);
    int L, m0; block_map(b, L, m0);
    const float* obj = (L == 0) ? o0 : ((L == 1) ? o1 : o2);
    const float* cls = (L == 0) ? c0 : ((L == 1) ? c1 : c2);
    const float4* cls4 = (const float4*)cls;

    // ================= PHASE A: histogram =================
    {
        u32* h = (u32*)smem64;                 // 8*257
        u32* alist = h + 8 * 257;              // 256
        float* slist = (float*)(alist + 256);  // 256
        u32* nshp = (u32*)(slist + 256);
        for (int k = tid; k < 8 * 257; k += 256) h[k] = 0u;
        if (tid == 0) *nshp = 0u;
        __syncthreads();
        float so = sigm(obj[m0 + tid]);
        bool pass = __float_as_uint(so) >= PB_HALF;  // p <= so
        u64 mask = __ballot(pass);
        u32 pc = (u32)__popcll(mask);
        u32 wbase = 0;
        if (lane == 0 && pc) wbase = atomicAdd(nshp, pc);
        wbase = (u32)__shfl((int)wbase, 0);
        if (pass) {
            u32 off = (u32)__popcll(mask & ((1ull << lane) - 1ull));
            alist[wbase + off] = (u32)tid;
            slist[wbase + off] = so;
        }
        __syncthreads();
        int n = (int)*nshp;
        u32 rep = (u32)(tid & 7);
        for (int i = tid; i < n * 20; i += 256) {
            int j = i / 20, k = i - j * 20;
            int a = m0 + (int)alist[j];
            float soj = slist[j];
            float4 v = cls4[a * 20 + k];
            float vv[4] = {v.x, v.y, v.z, v.w};
#pragma unroll
            for (int q = 0; q < 4; ++q) {
                float p = soj * sigm(vv[q]);
                u32 pb = __float_as_uint(p);
                if (pb >= PB_HALF) {
                    u32 bin = min((pb >> 15) - 0x7E00u, 255u);
                    atomicAdd(&h[rep * 257 + bin], 1u);
                }
            }
        }
        __syncthreads();
        if (tid < 256) {
            u32 s = 0;
            for (int r = 0; r < 8; ++r) s += h[r * 257 + tid];
            if (s) atomicAdd(&whist[L * 256 + tid], s);  // device-scope RMW, coherent
        }
    }
    __syncthreads();
    if (tid == 0) { arrive(doneA); wait_for(doneA, NBLK); }
    __syncthreads();

    // ================= PHASE B: filter =================
    {
        u32* sh = (u32*)smem64;               // 256
        u32* alist = sh + 256;                // 256
        float* slist = (float*)(alist + 256); // 256
        int* cutbin = (int*)(slist + 256);
        u32* thrsh = (u32*)(cutbin + 1);
        u32* nshp = thrsh + 1;
        if (tid == 0) { *cutbin = -1; *nshp = 0u; }
        sh[tid] = cload32(&whist[L * 256 + tid]);
        __syncthreads();
        for (int off = 1; off < 256; off <<= 1) {
            u32 v = (tid + off < 256) ? sh[tid + off] : 0u;
            __syncthreads();
            sh[tid] += v;
            __syncthreads();
        }
        if (sh[tid] >= 1000u) atomicMax(cutbin, tid);
        __syncthreads();
        if (tid == 0) {
            // one-bin margin below the rank-1000 bin covers sqrt-tie hazards
            *thrsh = (*cutbin >= 0) ? (PB_HALF + ((u32)*cutbin << 15)) - 0x8000u
                                    : PB_QUARTER;
        }
        __syncthreads();
        u32 thr = *thrsh;
        float so = sigm(obj[m0 + tid]);
        bool pass = __float_as_uint(so) >= thr;  // p <= so
        u64 mask = __ballot(pass);
        u32 pc = (u32)__popcll(mask);
        u32 wbase = 0;
        if (lane == 0 && pc) wbase = atomicAdd(nshp, pc);
        wbase = (u32)__shfl((int)wbase, 0);
        if (pass) {
            u32 off = (u32)__popcll(mask & ((1ull << lane) - 1ull));
            alist[wbase + off] = (u32)tid;
            slist[wbase + off] = so;
        }
        __syncthreads();
        int n = (int)*nshp;
        for (int i = tid; i < n * 20; i += 256) {
            int j = i / 20, k = i - j * 20;
            int a = m0 + (int)alist[j];
            float soj = slist[j];
            float4 v = cls4[a * 20 + k];
            float vv[4] = {v.x, v.y, v.z, v.w};
#pragma unroll
            for (int q = 0; q < 4; ++q) {
                float p = soj * sigm(vv[q]);
                u32 pb = __float_as_uint(p);
                bool emit = (pb >= thr);
                u64 em = __ballot(emit);  // active lanes are a prefix: lane0 live
                if (em) {
                    u32 cw = (u32)__popcll(em);
                    u32 base = 0;
                    if (lane == 0) base = atomicAdd(&wcnt[L], cw);  // 1 RMW/wave
                    base = (u32)__shfl((int)base, 0);
                    if (emit) {
                        u32 slot = base + (u32)__popcll(em & ((1ull << lane) - 1ull));
                        if (slot < CAND_CAP) {
                            float s = sqrtf(p);
                            u32 sb = __float_as_uint(s);
                            u32 idx = (u32)(a * NCLS + (k * 4 + q));
                            cstore64(&wcand[L * CAND_CAP + slot],
                                     ((u64)(sb ^ 0xFFFFFFFFu) << 32) | idx);
                        }
                    }
                }
            }
        }
    }
    __syncthreads();
    if (tid == 0) arrive(doneB);

    // ================= PHASE C: rank-select (blocks 0..47) =================
    if (b < 48) {
        if (tid == 0) wait_for(doneB, NBLK);
        __syncthreads();
        u64* s = smem64;
        int RL = b >> 4, part = b & 15;
        int n = (int)min(cload32(&wcnt[RL]), (u32)CAND_CAP);
        if (part * 256 < n) {
            for (int j = tid; j < n; j += 256) s[j] = cload64(&wcand[RL * CAND_CAP + j]);
            __syncthreads();
            int i = part * 256 + tid;
            if (i < n) {
                u64 mykey = s[i];
                int rank = 0;
#pragma unroll 4
                for (int j = 0; j < n; ++j) rank += (s[j] < mykey);  // LDS broadcast
                if (rank < 1000) cstore64(&wsel[RL * 1000 + rank], mykey);
            }
        }
        __syncthreads();
        if (tid == 0) arrive(doneC);
        return;
    }

    // ================= PHASE D: merge + decode + NMS (blocks 48..127) =====
    if (b >= 128) return;
    {
        int c = b - 48;  // class id
        u64* k = smem64;                        // [0..3000) keys
        u64* ckey = smem64 + 3000;              // [3000..3256) class keys
        u32* cidx = (u32*)(smem64 + 3256);      // [3256..3384) original idx
        u32* ncp = (u32*)(smem64 + 3384);
        if (tid == 0) { *ncp = 0u; wait_for(doneC, 48); }
        __syncthreads();
        for (int i = tid; i < NTOT; i += 256) {
            u64 S = cload64(&wsel[i]);
            u64 key = (S & 0xFFFFFFFF00000000ull) | (u32)i;
            k[i] = key;
            u32 idx = (u32)S;
            if ((int)(idx % NCLS) == c) {
                u32 p = atomicAdd(ncp, 1u);
                if (p < 256) { ckey[p] = key; cidx[p] = idx; }
            }
        }
        __syncthreads();
        int nc = (int)min(*ncp, 256u);
        // per-thread: class rank r + global rank g (needs full k[])
        int g = -1, r = 0;
        u32 myidx = 0;
        u64 mykey = 0;
        if (tid < nc) {
            mykey = ckey[tid];
            myidx = cidx[tid];
            for (int j = 0; j < nc; ++j) r += (ckey[j] < mykey);
            int t = (int)(u32)mykey;
            int ML = t / 1000;
            g = t - ML * 1000;
            for (int O = 0; O < 3; ++O) {
                if (O == ML) continue;
                int lo = 0, hi = 1000;
                while (lo < hi) {
                    int mid = (lo + hi) >> 1;
                    if (k[O * 1000 + mid] < mykey) lo = mid + 1; else hi = mid;
                }
                g += lo;
            }
        }
        __syncthreads();  // k[] no longer needed; reuse its space
        u32* garr = (u32*)smem64;              // 256
        u32* invp = (u32*)(smem64 + 64);       // 256
        float* bx = (float*)(smem64 + 512);    // 256*4 floats
        if (tid < nc) {
            garr[tid] = (u32)g;
            invp[r] = (u32)tid;
            int t = (int)(u32)mykey;
            int ML = t / 1000;
            u32 bits = (u32)(mykey >> 32) ^ 0xFFFFFFFFu;
            float score = __uint_as_float(bits);
            int m = (int)(myidx / NCLS);
            int w = (ML == 0) ? 320 : ((ML == 1) ? 160 : 80);
            float st = (ML == 0) ? 8.0f : ((ML == 1) ? 16.0f : 32.0f);
            const float* reg = (ML == 0) ? r0 : ((ML == 1) ? r1 : r2);
            int x = m % w, y = m / w;
            float rv0 = reg[m * 4 + 0], rv1 = reg[m * 4 + 1];
            float rv2 = reg[m * 4 + 2], rv3 = reg[m * 4 + 3];
            float ax = ((float)x + 0.5f) * st;
            float ay = ((float)y + 0.5f) * st;
            float cx = ax + rv0 * st;
            float cy = ay + rv1 * st;
            float bw = expf(rv2) * st;
            float bh = expf(rv3) * st;
            float hx = 0.5f * bw, hy = 0.5f * bh;
            float x1 = cx - hx, y1 = cy - hy, x2 = cx + hx, y2 = cy + hy;
            out[g * 4 + 0] = x1; out[g * 4 + 1] = y1;
            out[g * 4 + 2] = x2; out[g * 4 + 3] = y2;
            out[12000 + g] = score;
            out[15000 + g] = (float)c;
            float off = (float)c * 8192.0f;
            bx[tid * 4 + 0] = x1 + off; bx[tid * 4 + 1] = y1 + off;
            bx[tid * 4 + 2] = x2 + off; bx[tid * 4 + 3] = y2 + off;
        }
        __syncthreads();
        // greedy NMS in score order, 1 wave
        if (tid < 64) {
            int K = (nc + 63) >> 6;
            u32 alive = 0;
            for (int kk = 0; kk < K; ++kk) {
                int p = tid + (kk << 6);
                if (p < nc) {
                    u32 bits = (u32)(ckey[invp[p]] >> 32) ^ 0xFFFFFFFFu;
                    if (__uint_as_float(bits) > 0.05f) alive |= (1u << kk);
                }
            }
            for (int a = 0; a < nc; ++a) {
                u32 owner = (u32)__shfl((int)alive, a & 63);
                if ((owner >> (a >> 6)) & 1u) {
                    int ra = (int)invp[a];
                    float a0 = bx[ra * 4 + 0], a1 = bx[ra * 4 + 1];
                    float a2 = bx[ra * 4 + 2], a3 = bx[ra * 4 + 3];
                    float areaA = (a2 - a0) * (a3 - a1);
                    for (int kk = (a >> 6); kk < K; ++kk) {
                        int p = tid + (kk << 6);
                        if (p > a && p < nc && ((alive >> kk) & 1u)) {
                            int rp = (int)invp[p];
                            float b0 = bx[rp * 4 + 0], b1 = bx[rp * 4 + 1];
                            float b2 = bx[rp * 4 + 2], b3 = bx[rp * 4 + 3];
                            float areaB = (b2 - b0) * (b3 - b1);
                            float ltx = fmaxf(a0, b0), lty = fmaxf(a1, b1);
                            float rbx = fminf(a2, b2), rby = fminf(a3, b3);
                            float wx = fmaxf(rbx - ltx, 0.0f), wy = fmaxf(rby - lty, 0.0f);
                            float inter = wx * wy;
                            float denom = ((areaA + areaB) - inter) + 1e-9f;
                            float iou = inter / denom;
                            if (iou > 0.6f) alive &= ~(1u << kk);
                        }
                    }
                }
            }
            for (int kk = 0; kk < K; ++kk) {
                int p = tid + (kk << 6);
                if (p < nc)
                    out[18000 + garr[invp[p]]] = ((alive >> kk) & 1u) ? 1.0f : 0.0f;
            }
        }
    }
}

extern "C" void kernel_launch(void* const* d_in, const int* in_sizes, int n_in,
                              void* d_out, int out_size, void* d_ws, size_t ws_size,
                              hipStream_t stream) {
    const float* obj0 = (const float*)d_in[0];
    const float* cls0 = (const float*)d_in[1];
    const float* reg0 = (const float*)d_in[2];
    const float* obj1 = (const float*)d_in[3];
    const float* cls1 = (const float*)d_in[4];
    const float* reg1 = (const float*)d_in[5];
    const float* obj2 = (const float*)d_in[6];
    const float* cls2 = (const float*)d_in[7];
    const float* reg2 = (const float*)d_in[8];
    float* out = (float*)d_out;
    char* ws = (char*)d_ws;

    u32* hist  = (u32*)(ws + WS_HIST);
    u32* cnt   = (u32*)(ws + WS_CNT);
    u32* doneA = (u32*)(ws + WS_DONEA);
    u32* doneB = (u32*)(ws + WS_DONEB);
    u32* doneC = (u32*)(ws + WS_DONEC);
    u64* cand  = (u64*)(ws + WS_CAND);
    u64* sel   = (u64*)(ws + WS_SEL);

    hipMemsetAsync(ws, 0, 4096, stream);  // hist + cnt + flags
    fused_kernel<<<NBLK, 256, 0, stream>>>(obj0, cls0, reg0, obj1, cls1, reg1,
                                           obj2, cls2, reg2, out,
                                           hist, cnt, doneA, doneB, doneC,
                                           cand, sel);
}

// Round 8
// 200.972 us; speedup vs baseline: 2.2538x; 1.1692x over previous
//
#include <hip/hip_runtime.h>

typedef unsigned int u32;
typedef unsigned long long u64;

#define NCLS 80
#define NTOT 3000
#define CAND_CAP 4096

// ---- workspace layout (bytes); first 4096 zeroed by memsetAsync ----
#define WS_HIST   0       // 768 u32
#define WS_CNT    3072    // 3 u32
#define WS_DONEC  3456    // u32 (own cache line)
#define WS_CAND   4096    // 3*4096 u64
#define WS_SEL    102400  // 3000 u64

// hist bins: p in [0.5,1.0), bin = (pb>>15) - 0x7E00, 256 bins.
#define PB_HALF    0x3F000000u
#define PB_QUARTER 0x3E800000u

__device__ __forceinline__ float sigm(float x) {
#pragma clang fp contract(off)
    return 1.0f / (1.0f + expf(-x));
}

// agent-scope accessors (only used across the intra-K3 flag barrier)
__device__ __forceinline__ u64 cload64(const u64* p) {
    return __hip_atomic_load(p, __ATOMIC_RELAXED, __HIP_MEMORY_SCOPE_AGENT);
}
__device__ __forceinline__ void cstore64(u64* p, u64 v) {
    __hip_atomic_store(p, v, __ATOMIC_RELAXED, __HIP_MEMORY_SCOPE_AGENT);
}
__device__ __forceinline__ void arrive(u32* flag) {
    __hip_atomic_fetch_add(flag, 1u, __ATOMIC_RELEASE, __HIP_MEMORY_SCOPE_AGENT);
}
__device__ __forceinline__ void wait_for(u32* flag, u32 target) {
    int it = 0;
    while (__hip_atomic_load(flag, __ATOMIC_RELAXED, __HIP_MEMORY_SCOPE_AGENT) < target
           && it++ < (1 << 24)) {
        __builtin_amdgcn_s_sleep(2);
    }
    (void)__hip_atomic_load(flag, __ATOMIC_ACQUIRE, __HIP_MEMORY_SCOPE_AGENT);
}

// 1050 blocks x 128 rows: L0 800 blocks, L1 200, L2 50.
__device__ __forceinline__ void block_map128(int b, int& L, int& m0) {
    if (b < 800)       { L = 0; m0 = b * 128; }
    else if (b < 1000) { L = 1; m0 = (b - 800) * 128; }
    else               { L = 2; m0 = (b - 1000) * 128; }
}

// ---- K1: histogram of p = sig(obj)*sig(cls) over [0.5,1); row-skip on sig(obj) ----
__global__ __launch_bounds__(256) void hist_kernel(
    const float* __restrict__ o0, const float* __restrict__ c0,
    const float* __restrict__ o1, const float* __restrict__ c1,
    const float* __restrict__ o2, const float* __restrict__ c2,
    u32* __restrict__ whist) {
#pragma clang fp contract(off)
    __shared__ u32 h[8 * 257];
    __shared__ u32 alist[128];
    __shared__ float slist[128];
    __shared__ u32 nsh;
    int tid = threadIdx.x;
    int b = (int)blockIdx.x;
    int L, m0; block_map128(b, L, m0);
    const float* obj = (L == 0) ? o0 : ((L == 1) ? o1 : o2);
    const float* cls = (L == 0) ? c0 : ((L == 1) ? c1 : c2);
    const float4* cls4 = (const float4*)cls;
    for (int k = tid; k < 8 * 257; k += 256) h[k] = 0u;
    if (tid == 0) nsh = 0u;
    __syncthreads();
    if (tid < 128) {
        u32 lane = (u32)(tid & 63);
        float so = sigm(obj[m0 + tid]);
        bool pass = __float_as_uint(so) >= PB_HALF;  // p <= so
        u64 mask = __ballot(pass);
        u32 pc = (u32)__popcll(mask);
        u32 wbase = 0;
        if (lane == 0 && pc) wbase = atomicAdd(&nsh, pc);
        wbase = (u32)__shfl((int)wbase, 0);
        if (pass) {
            u32 off = (u32)__popcll(mask & ((1ull << lane) - 1ull));
            alist[wbase + off] = (u32)tid;
            slist[wbase + off] = so;
        }
    }
    __syncthreads();
    int n = (int)nsh;
    u32 rep = (u32)(tid & 7);
#pragma unroll 4
    for (int i = tid; i < n * 20; i += 256) {
        int j = i / 20, k = i - j * 20;
        int a = m0 + (int)alist[j];
        float soj = slist[j];
        float4 v = cls4[a * 20 + k];
        float vv[4] = {v.x, v.y, v.z, v.w};
#pragma unroll
        for (int q = 0; q < 4; ++q) {
            float p = soj * sigm(vv[q]);
            u32 pb = __float_as_uint(p);
            if (pb >= PB_HALF) {
                u32 bin = min((pb >> 15) - 0x7E00u, 255u);
                atomicAdd(&h[rep * 257 + bin], 1u);
            }
        }
    }
    __syncthreads();
    if (tid < 256) {
        u32 s = 0;
        for (int r = 0; r < 8; ++r) s += h[r * 257 + tid];
        if (s) atomicAdd(&whist[L * 256 + tid], s);
    }
}

// ---- K2: filter — inline cutoff (suffix scan of hist), row-skip, emit candidates ----
__global__ __launch_bounds__(256) void filter_kernel(
    const float* __restrict__ o0, const float* __restrict__ c0,
    const float* __restrict__ o1, const float* __restrict__ c1,
    const float* __restrict__ o2, const float* __restrict__ c2,
    const u32* __restrict__ whist, u32* __restrict__ wcnt, u64* __restrict__ wcand) {
#pragma clang fp contract(off)
    __shared__ u32 sh[256];
    __shared__ u32 alist[128];
    __shared__ float slist[128];
    __shared__ int cutbin;
    __shared__ u32 thrsh, nsh;
    int tid = threadIdx.x;
    int b = (int)blockIdx.x;
    u32 lane = (u32)(tid & 63);
    int L, m0; block_map128(b, L, m0);
    const float* obj = (L == 0) ? o0 : ((L == 1) ? o1 : o2);
    const float* cls = (L == 0) ? c0 : ((L == 1) ? c1 : c2);
    const float4* cls4 = (const float4*)cls;
    if (tid == 0) { cutbin = -1; nsh = 0u; }
    sh[tid] = whist[L * 256 + tid];
    __syncthreads();
    for (int off = 1; off < 256; off <<= 1) {
        u32 v = (tid + off < 256) ? sh[tid + off] : 0u;
        __syncthreads();
        sh[tid] += v;
        __syncthreads();
    }
    if (sh[tid] >= 1000u) atomicMax(&cutbin, tid);
    __syncthreads();
    if (tid == 0) {
        // one-bin margin below the rank-1000 bin covers sqrt-tie hazards
        thrsh = (cutbin >= 0) ? (PB_HALF + ((u32)cutbin << 15)) - 0x8000u
                              : PB_QUARTER;
    }
    __syncthreads();
    u32 thr = thrsh;
    if (tid < 128) {
        float so = sigm(obj[m0 + tid]);
        bool pass = __float_as_uint(so) >= thr;  // p <= so
        u64 mask = __ballot(pass);
        u32 pc = (u32)__popcll(mask);
        u32 wbase = 0;
        if (lane == 0 && pc) wbase = atomicAdd(&nsh, pc);
        wbase = (u32)__shfl((int)wbase, 0);
        if (pass) {
            u32 off = (u32)__popcll(mask & ((1ull << lane) - 1ull));
            alist[wbase + off] = (u32)tid;
            slist[wbase + off] = so;
        }
    }
    __syncthreads();
    int n = (int)nsh;
#pragma unroll 4
    for (int i = tid; i < n * 20; i += 256) {
        int j = i / 20, k = i - j * 20;
        int a = m0 + (int)alist[j];
        float soj = slist[j];
        float4 v = cls4[a * 20 + k];
        float vv[4] = {v.x, v.y, v.z, v.w};
#pragma unroll
        for (int q = 0; q < 4; ++q) {
            float p = soj * sigm(vv[q]);
            u32 pb = __float_as_uint(p);
            bool emit = (pb >= thr);
            u64 em = __ballot(emit);  // active lanes are a tid-prefix of the wave
            if (em) {
                u32 cw = (u32)__popcll(em);
                u32 base = 0;
                if (lane == 0) base = atomicAdd(&wcnt[L], cw);  // 1 RMW per wave
                base = (u32)__shfl((int)base, 0);
                if (emit) {
                    u32 slot = base + (u32)__popcll(em & ((1ull << lane) - 1ull));
                    if (slot < CAND_CAP) {
                        float s = sqrtf(p);
                        u32 sb = __float_as_uint(s);
                        u32 idx = (u32)(a * NCLS + (k * 4 + q));
                        wcand[L * CAND_CAP + slot] = ((u64)(sb ^ 0xFFFFFFFFu) << 32) | idx;
                    }
                }
            }
        }
    }
}

// ---- K3: blocks 0..47 rank-select; flag; blocks 48..127 merge+decode+NMS ----
__global__ __launch_bounds__(256) void rank_nms_kernel(
    const u32* __restrict__ wcnt, const u64* __restrict__ wcand,
    u64* __restrict__ wsel, u32* __restrict__ doneC,
    const float* __restrict__ r0, const float* __restrict__ r1,
    const float* __restrict__ r2, float* __restrict__ out) {
#pragma clang fp contract(off)
    __shared__ u64 smem64[4096];  // 32 KB
    int tid = threadIdx.x;
    int b = (int)blockIdx.x;

    if (b < 48) {
        // exact top-1000 per level by rank-counting (keys unique)
        u64* s = smem64;
        int RL = b >> 4, part = b & 15;
        int n = (int)min(wcnt[RL], (u32)CAND_CAP);
        if (part * 256 < n) {
            for (int j = tid; j < n; j += 256) s[j] = wcand[RL * CAND_CAP + j];
            __syncthreads();
            int i = part * 256 + tid;
            if (i < n) {
                u64 mykey = s[i];
                int rank = 0;
#pragma unroll 4
                for (int j = 0; j < n; ++j) rank += (s[j] < mykey);  // LDS broadcast
                if (rank < 1000) cstore64(&wsel[RL * 1000 + rank], mykey);
            }
        }
        __syncthreads();  // drains vmcnt: this block's sel stores retired
        if (tid == 0) arrive(doneC);
        return;
    }

    // ---- merge + decode + per-class NMS (one block per class) ----
    int c = b - 48;
    u64* k = smem64;                        // [0..3000) keys
    u64* ckey = smem64 + 3000;              // [3000..3256) class keys
    u32* cidx = (u32*)(smem64 + 3256);      // 256 original idx
    u32* ncp = (u32*)(smem64 + 3384);
    if (tid == 0) { *ncp = 0u; wait_for(doneC, 48); }
    __syncthreads();
    for (int i = tid; i < NTOT; i += 256) {
        u64 S = cload64(&wsel[i]);
        u64 key = (S & 0xFFFFFFFF00000000ull) | (u32)i;
        k[i] = key;
        u32 idx = (u32)S;
        if ((int)(idx % NCLS) == c) {
            u32 p = atomicAdd(ncp, 1u);
            if (p < 256) { ckey[p] = key; cidx[p] = idx; }
        }
    }
    __syncthreads();
    int nc = (int)min(*ncp, 256u);
    int g = -1, r = 0;
    u32 myidx = 0;
    u64 mykey = 0;
    if (tid < nc) {
        mykey = ckey[tid];
        myidx = cidx[tid];
        for (int j = 0; j < nc; ++j) r += (ckey[j] < mykey);
        int t = (int)(u32)mykey;
        int ML = t / 1000;
        g = t - ML * 1000;
        for (int O = 0; O < 3; ++O) {
            if (O == ML) continue;
            int lo = 0, hi = 1000;
            while (lo < hi) {
                int mid = (lo + hi) >> 1;
                if (k[O * 1000 + mid] < mykey) lo = mid + 1; else hi = mid;
            }
            g += lo;
        }
    }
    __syncthreads();  // k[] no longer needed; reuse its space
    u32* garr = (u32*)smem64;              // 256
    u32* invp = (u32*)(smem64 + 64);       // 256
    float* bx = (float*)(smem64 + 512);    // 256*4 floats
    if (tid < nc) {
        garr[tid] = (u32)g;
        invp[r] = (u32)tid;
        int t = (int)(u32)mykey;
        int ML = t / 1000;
        u32 bits = (u32)(mykey >> 32) ^ 0xFFFFFFFFu;
        float score = __uint_as_float(bits);
        int m = (int)(myidx / NCLS);
        int w = (ML == 0) ? 320 : ((ML == 1) ? 160 : 80);
        float st = (ML == 0) ? 8.0f : ((ML == 1) ? 16.0f : 32.0f);
        const float* reg = (ML == 0) ? r0 : ((ML == 1) ? r1 : r2);
        int x = m % w, y = m / w;
        float rv0 = reg[m * 4 + 0], rv1 = reg[m * 4 + 1];
        float rv2 = reg[m * 4 + 2], rv3 = reg[m * 4 + 3];
        float ax = ((float)x + 0.5f) * st;
        float ay = ((float)y + 0.5f) * st;
        float cx = ax + rv0 * st;
        float cy = ay + rv1 * st;
        float bw = expf(rv2) * st;
        float bh = expf(rv3) * st;
        float hx = 0.5f * bw, hy = 0.5f * bh;
        float x1 = cx - hx, y1 = cy - hy, x2 = cx + hx, y2 = cy + hy;
        out[g * 4 + 0] = x1; out[g * 4 + 1] = y1;
        out[g * 4 + 2] = x2; out[g * 4 + 3] = y2;
        out[12000 + g] = score;
        out[15000 + g] = (float)c;
        float off = (float)c * 8192.0f;
        bx[tid * 4 + 0] = x1 + off; bx[tid * 4 + 1] = y1 + off;
        bx[tid * 4 + 2] = x2 + off; bx[tid * 4 + 3] = y2 + off;
    }
    __syncthreads();
    // greedy NMS in score order, 1 wave
    if (tid < 64) {
        int K = (nc + 63) >> 6;
        u32 alive = 0;
        for (int kk = 0; kk < K; ++kk) {
            int p = tid + (kk << 6);
            if (p < nc) {
                u32 bits = (u32)(ckey[invp[p]] >> 32) ^ 0xFFFFFFFFu;
                if (__uint_as_float(bits) > 0.05f) alive |= (1u << kk);
            }
        }
        for (int a = 0; a < nc; ++a) {
            u32 owner = (u32)__shfl((int)alive, a & 63);
            if ((owner >> (a >> 6)) & 1u) {
                int ra = (int)invp[a];
                float a0 = bx[ra * 4 + 0], a1 = bx[ra * 4 + 1];
                float a2 = bx[ra * 4 + 2], a3 = bx[ra * 4 + 3];
                float areaA = (a2 - a0) * (a3 - a1);
                for (int kk = (a >> 6); kk < K; ++kk) {
                    int p = tid + (kk << 6);
                    if (p > a && p < nc && ((alive >> kk) & 1u)) {
                        int rp = (int)invp[p];
                        float b0 = bx[rp * 4 + 0], b1 = bx[rp * 4 + 1];
                        float b2 = bx[rp * 4 + 2], b3 = bx[rp * 4 + 3];
                        float areaB = (b2 - b0) * (b3 - b1);
                        float ltx = fmaxf(a0, b0), lty = fmaxf(a1, b1);
                        float rbx = fminf(a2, b2), rby = fminf(a3, b3);
                        float wx = fmaxf(rbx - ltx, 0.0f), wy = fmaxf(rby - lty, 0.0f);
                        float inter = wx * wy;
                        float denom = ((areaA + areaB) - inter) + 1e-9f;
                        float iou = inter / denom;
                        if (iou > 0.6f) alive &= ~(1u << kk);
                    }
                }
            }
        }
        for (int kk = 0; kk < K; ++kk) {
            int p = tid + (kk << 6);
            if (p < nc)
                out[18000 + garr[invp[p]]] = ((alive >> kk) & 1u) ? 1.0f : 0.0f;
        }
    }
}

extern "C" void kernel_launch(void* const* d_in, const int* in_sizes, int n_in,
                              void* d_out, int out_size, void* d_ws, size_t ws_size,
                              hipStream_t stream) {
    const float* obj0 = (const float*)d_in[0];
    const float* cls0 = (const float*)d_in[1];
    const float* reg0 = (const float*)d_in[2];
    const float* obj1 = (const float*)d_in[3];
    const float* cls1 = (const float*)d_in[4];
    const float* reg1 = (const float*)d_in[5];
    const float* obj2 = (const float*)d_in[6];
    const float* cls2 = (const float*)d_in[7];
    const float* reg2 = (const float*)d_in[8];
    float* out = (float*)d_out;
    char* ws = (char*)d_ws;

    u32* hist  = (u32*)(ws + WS_HIST);
    u32* cnt   = (u32*)(ws + WS_CNT);
    u32* doneC = (u32*)(ws + WS_DONEC);
    u64* cand  = (u64*)(ws + WS_CAND);
    u64* sel   = (u64*)(ws + WS_SEL);

    hipMemsetAsync(ws, 0, 4096, stream);  // hist + cnt + doneC
    hist_kernel<<<1050, 256, 0, stream>>>(obj0, cls0, obj1, cls1, obj2, cls2, hist);
    filter_kernel<<<1050, 256, 0, stream>>>(obj0, cls0, obj1, cls1, obj2, cls2,
                                            hist, cnt, cand);
    rank_nms_kernel<<<128, 256, 0, stream>>>(cnt, cand, sel, doneC,
                                             reg0, reg1, reg2, out);
}

// Round 9
// 200.142 us; speedup vs baseline: 2.2632x; 1.0041x over previous
//
#include <hip/hip_runtime.h>

typedef unsigned int u32;
typedef unsigned long long u64;

#define NCLS 80
#define NTOT 3000
#define CAND_CAP 4096

// ---- workspace layout (bytes); first 4096 zeroed by memsetAsync ----
#define WS_HIST   0       // 768 u32
#define WS_CNT    3072    // 3 u32
#define WS_DONEC  3456    // u32 (own cache line)
#define WS_CAND   4096    // 3*4096 u64
#define WS_SEL    102400  // 3000 u64

// hist bins: p in [0.5,1.0), bin = (pb>>15) - 0x7E00, 256 bins.
#define PB_HALF    0x3F000000u
#define PB_QUARTER 0x3E800000u

__device__ __forceinline__ float sigm(float x) {
#pragma clang fp contract(off)
    return 1.0f / (1.0f + expf(-x));
}

// agent-scope RELAXED accessors. These compile to cache-bypassing (sc0/sc1)
// loads/stores serviced at the LLC. Ordering across the intra-K3 barrier is
// by construction: __syncthreads() drains vmcnt(0) (stores visible at the
// coherent point) BEFORE the relaxed flag increment; consumers poll with a
// bypass load and then read the data with bypass loads. No release/acquire
// -> no buffer_wbl2 / buffer_inv storms (the ~40us cost seen in R5-R8).
__device__ __forceinline__ u64 cload64(const u64* p) {
    return __hip_atomic_load(p, __ATOMIC_RELAXED, __HIP_MEMORY_SCOPE_AGENT);
}
__device__ __forceinline__ void cstore64(u64* p, u64 v) {
    __hip_atomic_store(p, v, __ATOMIC_RELAXED, __HIP_MEMORY_SCOPE_AGENT);
}
__device__ __forceinline__ void arrive(u32* flag) {
    __hip_atomic_fetch_add(flag, 1u, __ATOMIC_RELAXED, __HIP_MEMORY_SCOPE_AGENT);
}
__device__ __forceinline__ void wait_for(u32* flag, u32 target) {
    int it = 0;
    while (__hip_atomic_load(flag, __ATOMIC_RELAXED, __HIP_MEMORY_SCOPE_AGENT) < target
           && it++ < (1 << 24)) {
        __builtin_amdgcn_s_sleep(2);
    }
}

// 1050 blocks x 128 rows: L0 800 blocks, L1 200, L2 50.
__device__ __forceinline__ void block_map128(int b, int& L, int& m0) {
    if (b < 800)       { L = 0; m0 = b * 128; }
    else if (b < 1000) { L = 1; m0 = (b - 800) * 128; }
    else               { L = 2; m0 = (b - 1000) * 128; }
}

// ---- K1: histogram of p = sig(obj)*sig(cls) over [0.5,1); row-skip on sig(obj) ----
__global__ __launch_bounds__(256) void hist_kernel(
    const float* __restrict__ o0, const float* __restrict__ c0,
    const float* __restrict__ o1, const float* __restrict__ c1,
    const float* __restrict__ o2, const float* __restrict__ c2,
    u32* __restrict__ whist) {
#pragma clang fp contract(off)
    __shared__ u32 h[8 * 257];
    __shared__ u32 alist[128];
    __shared__ float slist[128];
    __shared__ u32 nsh;
    int tid = threadIdx.x;
    int b = (int)blockIdx.x;
    int L, m0; block_map128(b, L, m0);
    const float* obj = (L == 0) ? o0 : ((L == 1) ? o1 : o2);
    const float* cls = (L == 0) ? c0 : ((L == 1) ? c1 : c2);
    const float4* cls4 = (const float4*)cls;
    for (int k = tid; k < 8 * 257; k += 256) h[k] = 0u;
    if (tid == 0) nsh = 0u;
    __syncthreads();
    if (tid < 128) {
        u32 lane = (u32)(tid & 63);
        float so = sigm(obj[m0 + tid]);
        bool pass = __float_as_uint(so) >= PB_HALF;  // p <= so
        u64 mask = __ballot(pass);
        u32 pc = (u32)__popcll(mask);
        u32 wbase = 0;
        if (lane == 0 && pc) wbase = atomicAdd(&nsh, pc);
        wbase = (u32)__shfl((int)wbase, 0);
        if (pass) {
            u32 off = (u32)__popcll(mask & ((1ull << lane) - 1ull));
            alist[wbase + off] = (u32)tid;
            slist[wbase + off] = so;
        }
    }
    __syncthreads();
    int n = (int)nsh;
    u32 rep = (u32)(tid & 7);
#pragma unroll 4
    for (int i = tid; i < n * 20; i += 256) {
        int j = i / 20, k = i - j * 20;
        int a = m0 + (int)alist[j];
        float soj = slist[j];
        float4 v = cls4[a * 20 + k];
        float vv[4] = {v.x, v.y, v.z, v.w};
#pragma unroll
        for (int q = 0; q < 4; ++q) {
            float p = soj * sigm(vv[q]);
            u32 pb = __float_as_uint(p);
            if (pb >= PB_HALF) {
                u32 bin = min((pb >> 15) - 0x7E00u, 255u);
                atomicAdd(&h[rep * 257 + bin], 1u);
            }
        }
    }
    __syncthreads();
    if (tid < 256) {
        u32 s = 0;
        for (int r = 0; r < 8; ++r) s += h[r * 257 + tid];
        if (s) atomicAdd(&whist[L * 256 + tid], s);
    }
}

// ---- K2: filter — inline cutoff (suffix scan of hist), row-skip, emit candidates ----
__global__ __launch_bounds__(256) void filter_kernel(
    const float* __restrict__ o0, const float* __restrict__ c0,
    const float* __restrict__ o1, const float* __restrict__ c1,
    const float* __restrict__ o2, const float* __restrict__ c2,
    const u32* __restrict__ whist, u32* __restrict__ wcnt, u64* __restrict__ wcand) {
#pragma clang fp contract(off)
    __shared__ u32 sh[256];
    __shared__ u32 alist[128];
    __shared__ float slist[128];
    __shared__ int cutbin;
    __shared__ u32 thrsh, nsh;
    int tid = threadIdx.x;
    int b = (int)blockIdx.x;
    u32 lane = (u32)(tid & 63);
    int L, m0; block_map128(b, L, m0);
    const float* obj = (L == 0) ? o0 : ((L == 1) ? o1 : o2);
    const float* cls = (L == 0) ? c0 : ((L == 1) ? c1 : c2);
    const float4* cls4 = (const float4*)cls;
    if (tid == 0) { cutbin = -1; nsh = 0u; }
    sh[tid] = whist[L * 256 + tid];
    __syncthreads();
    for (int off = 1; off < 256; off <<= 1) {
        u32 v = (tid + off < 256) ? sh[tid + off] : 0u;
        __syncthreads();
        sh[tid] += v;
        __syncthreads();
    }
    if (sh[tid] >= 1000u) atomicMax(&cutbin, tid);
    __syncthreads();
    if (tid == 0) {
        // one-bin margin below the rank-1000 bin covers sqrt-tie hazards
        thrsh = (cutbin >= 0) ? (PB_HALF + ((u32)cutbin << 15)) - 0x8000u
                              : PB_QUARTER;
    }
    __syncthreads();
    u32 thr = thrsh;
    if (tid < 128) {
        float so = sigm(obj[m0 + tid]);
        bool pass = __float_as_uint(so) >= thr;  // p <= so
        u64 mask = __ballot(pass);
        u32 pc = (u32)__popcll(mask);
        u32 wbase = 0;
        if (lane == 0 && pc) wbase = atomicAdd(&nsh, pc);
        wbase = (u32)__shfl((int)wbase, 0);
        if (pass) {
            u32 off = (u32)__popcll(mask & ((1ull << lane) - 1ull));
            alist[wbase + off] = (u32)tid;
            slist[wbase + off] = so;
        }
    }
    __syncthreads();
    int n = (int)nsh;
#pragma unroll 4
    for (int i = tid; i < n * 20; i += 256) {
        int j = i / 20, k = i - j * 20;
        int a = m0 + (int)alist[j];
        float soj = slist[j];
        float4 v = cls4[a * 20 + k];
        float vv[4] = {v.x, v.y, v.z, v.w};
#pragma unroll
        for (int q = 0; q < 4; ++q) {
            float p = soj * sigm(vv[q]);
            u32 pb = __float_as_uint(p);
            bool emit = (pb >= thr);
            u64 em = __ballot(emit);  // active lanes are a tid-prefix of the wave
            if (em) {
                u32 cw = (u32)__popcll(em);
                u32 base = 0;
                if (lane == 0) base = atomicAdd(&wcnt[L], cw);  // 1 RMW per wave
                base = (u32)__shfl((int)base, 0);
                if (emit) {
                    u32 slot = base + (u32)__popcll(em & ((1ull << lane) - 1ull));
                    if (slot < CAND_CAP) {
                        float s = sqrtf(p);
                        u32 sb = __float_as_uint(s);
                        u32 idx = (u32)(a * NCLS + (k * 4 + q));
                        wcand[L * CAND_CAP + slot] = ((u64)(sb ^ 0xFFFFFFFFu) << 32) | idx;
                    }
                }
            }
        }
    }
}

// ---- K3: blocks 0..47 rank-select; flag; blocks 48..127 merge+decode+NMS ----
__global__ __launch_bounds__(256) void rank_nms_kernel(
    const u32* __restrict__ wcnt, const u64* __restrict__ wcand,
    u64* __restrict__ wsel, u32* __restrict__ doneC,
    const float* __restrict__ r0, const float* __restrict__ r1,
    const float* __restrict__ r2, float* __restrict__ out) {
#pragma clang fp contract(off)
    __shared__ u64 smem64[4096];  // 32 KB
    int tid = threadIdx.x;
    int b = (int)blockIdx.x;

    if (b < 48) {
        // exact top-1000 per level by rank-counting (keys unique)
        u64* s = smem64;
        int RL = b >> 4, part = b & 15;
        int n = (int)min(wcnt[RL], (u32)CAND_CAP);
        if (part * 256 < n) {
            for (int j = tid; j < n; j += 256) s[j] = wcand[RL * CAND_CAP + j];
            __syncthreads();
            int i = part * 256 + tid;
            if (i < n) {
                u64 mykey = s[i];
                int rank = 0;
#pragma unroll 4
                for (int j = 0; j < n; ++j) rank += (s[j] < mykey);  // LDS broadcast
                if (rank < 1000) cstore64(&wsel[RL * 1000 + rank], mykey);
            }
        }
        __syncthreads();  // drains vmcnt(0): this block's bypass stores are LLC-visible
        if (tid == 0) arrive(doneC);
        return;
    }

    // ---- merge + decode + per-class NMS (one block per class) ----
    int c = b - 48;
    u64* k = smem64;                        // [0..3000) keys
    u64* ckey = smem64 + 3000;              // [3000..3256) class keys
    u32* cidx = (u32*)(smem64 + 3256);      // 256 original idx
    u32* ncp = (u32*)(smem64 + 3384);
    if (tid == 0) { *ncp = 0u; wait_for(doneC, 48); }
    __syncthreads();
    for (int i = tid; i < NTOT; i += 256) {
        u64 S = cload64(&wsel[i]);
        u64 key = (S & 0xFFFFFFFF00000000ull) | (u32)i;
        k[i] = key;
        u32 idx = (u32)S;
        if ((int)(idx % NCLS) == c) {
            u32 p = atomicAdd(ncp, 1u);
            if (p < 256) { ckey[p] = key; cidx[p] = idx; }
        }
    }
    __syncthreads();
    int nc = (int)min(*ncp, 256u);
    int g = -1, r = 0;
    u32 myidx = 0;
    u64 mykey = 0;
    if (tid < nc) {
        mykey = ckey[tid];
        myidx = cidx[tid];
        for (int j = 0; j < nc; ++j) r += (ckey[j] < mykey);
        int t = (int)(u32)mykey;
        int ML = t / 1000;
        g = t - ML * 1000;
        for (int O = 0; O < 3; ++O) {
            if (O == ML) continue;
            int lo = 0, hi = 1000;
            while (lo < hi) {
                int mid = (lo + hi) >> 1;
                if (k[O * 1000 + mid] < mykey) lo = mid + 1; else hi = mid;
            }
            g += lo;
        }
    }
    __syncthreads();  // k[] no longer needed; reuse its space
    u32* garr = (u32*)smem64;              // 256
    u32* invp = (u32*)(smem64 + 64);       // 256
    float* bx = (float*)(smem64 + 512);    // 256*4 floats
    if (tid < nc) {
        garr[tid] = (u32)g;
        invp[r] = (u32)tid;
        int t = (int)(u32)mykey;
        int ML = t / 1000;
        u32 bits = (u32)(mykey >> 32) ^ 0xFFFFFFFFu;
        float score = __uint_as_float(bits);
        int m = (int)(myidx / NCLS);
        int w = (ML == 0) ? 320 : ((ML == 1) ? 160 : 80);
        float st = (ML == 0) ? 8.0f : ((ML == 1) ? 16.0f : 32.0f);
        const float* reg = (ML == 0) ? r0 : ((ML == 1) ? r1 : r2);
        int x = m % w, y = m / w;
        float rv0 = reg[m * 4 + 0], rv1 = reg[m * 4 + 1];
        float rv2 = reg[m * 4 + 2], rv3 = reg[m * 4 + 3];
        float ax = ((float)x + 0.5f) * st;
        float ay = ((float)y + 0.5f) * st;
        float cx = ax + rv0 * st;
        float cy = ay + rv1 * st;
        float bw = expf(rv2) * st;
        float bh = expf(rv3) * st;
        float hx = 0.5f * bw, hy = 0.5f * bh;
        float x1 = cx - hx, y1 = cy - hy, x2 = cx + hx, y2 = cy + hy;
        out[g * 4 + 0] = x1; out[g * 4 + 1] = y1;
        out[g * 4 + 2] = x2; out[g * 4 + 3] = y2;
        out[12000 + g] = score;
        out[15000 + g] = (float)c;
        float off = (float)c * 8192.0f;
        bx[tid * 4 + 0] = x1 + off; bx[tid * 4 + 1] = y1 + off;
        bx[tid * 4 + 2] = x2 + off; bx[tid * 4 + 3] = y2 + off;
    }
    __syncthreads();
    // greedy NMS in score order, 1 wave
    if (tid < 64) {
        int K = (nc + 63) >> 6;
        u32 alive = 0;
        for (int kk = 0; kk < K; ++kk) {
            int p = tid + (kk << 6);
            if (p < nc) {
                u32 bits = (u32)(ckey[invp[p]] >> 32) ^ 0xFFFFFFFFu;
                if (__uint_as_float(bits) > 0.05f) alive |= (1u << kk);
            }
        }
        for (int a = 0; a < nc; ++a) {
            u32 owner = (u32)__shfl((int)alive, a & 63);
            if ((owner >> (a >> 6)) & 1u) {
                int ra = (int)invp[a];
                float a0 = bx[ra * 4 + 0], a1 = bx[ra * 4 + 1];
                float a2 = bx[ra * 4 + 2], a3 = bx[ra * 4 + 3];
                float areaA = (a2 - a0) * (a3 - a1);
                for (int kk = (a >> 6); kk < K; ++kk) {
                    int p = tid + (kk << 6);
                    if (p > a && p < nc && ((alive >> kk) & 1u)) {
                        int rp = (int)invp[p];
                        float b0 = bx[rp * 4 + 0], b1 = bx[rp * 4 + 1];
                        float b2 = bx[rp * 4 + 2], b3 = bx[rp * 4 + 3];
                        float areaB = (b2 - b0) * (b3 - b1);
                        float ltx = fmaxf(a0, b0), lty = fmaxf(a1, b1);
                        float rbx = fminf(a2, b2), rby = fminf(a3, b3);
                        float wx = fmaxf(rbx - ltx, 0.0f), wy = fmaxf(rby - lty, 0.0f);
                        float inter = wx * wy;
                        float denom = ((areaA + areaB) - inter) + 1e-9f;
                        float iou = inter / denom;
                        if (iou > 0.6f) alive &= ~(1u << kk);
                    }
                }
            }
        }
        for (int kk = 0; kk < K; ++kk) {
            int p = tid + (kk << 6);
            if (p < nc)
                out[18000 + garr[invp[p]]] = ((alive >> kk) & 1u) ? 1.0f : 0.0f;
        }
    }
}

extern "C" void kernel_launch(void* const* d_in, const int* in_sizes, int n_in,
                              void* d_out, int out_size, void* d_ws, size_t ws_size,
                              hipStream_t stream) {
    const float* obj0 = (const float*)d_in[0];
    const float* cls0 = (const float*)d_in[1];
    const float* reg0 = (const float*)d_in[2];
    const float* obj1 = (const float*)d_in[3];
    const float* cls1 = (const float*)d_in[4];
    const float* reg1 = (const float*)d_in[5];
    const float* obj2 = (const float*)d_in[6];
    const float* cls2 = (const float*)d_in[7];
    const float* reg2 = (const float*)d_in[8];
    float* out = (float*)d_out;
    char* ws = (char*)d_ws;

    u32* hist  = (u32*)(ws + WS_HIST);
    u32* cnt   = (u32*)(ws + WS_CNT);
    u32* doneC = (u32*)(ws + WS_DONEC);
    u64* cand  = (u64*)(ws + WS_CAND);
    u64* sel   = (u64*)(ws + WS_SEL);

    hipMemsetAsync(ws, 0, 4096, stream);  // hist + cnt + doneC
    hist_kernel<<<1050, 256, 0, stream>>>(obj0, cls0, obj1, cls1, obj2, cls2, hist);
    filter_kernel<<<1050, 256, 0, stream>>>(obj0, cls0, obj1, cls1, obj2, cls2,
                                            hist, cnt, cand);
    rank_nms_kernel<<<128, 256, 0, stream>>>(cnt, cand, sel, doneC,
                                             reg0, reg1, reg2, out);
}

// Round 10
// 196.297 us; speedup vs baseline: 2.3075x; 1.0196x over previous
//
#include <hip/hip_runtime.h>

typedef unsigned int u32;
typedef unsigned long long u64;

#define NCLS 80
#define NTOT 3000
#define CAND_CAP 4096

// ---- workspace layout (bytes); first 4096 zeroed by memsetAsync ----
#define WS_HIST   0       // 768 u32
#define WS_CNT    3072    // 3 u32
#define WS_CAND   4096    // 3*4096 u64
#define WS_SEL    102400  // 3000 u64

// hist bins: p in [0.5,1.0), bin = (pb>>15) - 0x7E00, 256 bins.
#define PB_HALF    0x3F000000u
#define PB_QUARTER 0x3E800000u

__device__ __forceinline__ float sigm(float x) {
#pragma clang fp contract(off)
    return 1.0f / (1.0f + expf(-x));
}

// 1050 blocks x 128 rows: L0 800 blocks, L1 200, L2 50.
__device__ __forceinline__ void block_map128(int b, int& L, int& m0) {
    if (b < 800)       { L = 0; m0 = b * 128; }
    else if (b < 1000) { L = 1; m0 = (b - 800) * 128; }
    else               { L = 2; m0 = (b - 1000) * 128; }
}

// ---- K1: histogram of p = sig(obj)*sig(cls) over [0.5,1); row-skip on sig(obj) ----
__global__ __launch_bounds__(256) void hist_kernel(
    const float* __restrict__ o0, const float* __restrict__ c0,
    const float* __restrict__ o1, const float* __restrict__ c1,
    const float* __restrict__ o2, const float* __restrict__ c2,
    u32* __restrict__ whist) {
#pragma clang fp contract(off)
    __shared__ u32 h[8 * 257];
    __shared__ u32 alist[128];
    __shared__ float slist[128];
    __shared__ u32 nsh;
    int tid = threadIdx.x;
    int b = (int)blockIdx.x;
    int L, m0; block_map128(b, L, m0);
    const float* obj = (L == 0) ? o0 : ((L == 1) ? o1 : o2);
    const float* cls = (L == 0) ? c0 : ((L == 1) ? c1 : c2);
    const float4* cls4 = (const float4*)cls;
    for (int k = tid; k < 8 * 257; k += 256) h[k] = 0u;
    if (tid == 0) nsh = 0u;
    __syncthreads();
    if (tid < 128) {
        u32 lane = (u32)(tid & 63);
        float so = sigm(obj[m0 + tid]);
        bool pass = __float_as_uint(so) >= PB_HALF;  // p <= so
        u64 mask = __ballot(pass);
        u32 pc = (u32)__popcll(mask);
        u32 wbase = 0;
        if (lane == 0 && pc) wbase = atomicAdd(&nsh, pc);
        wbase = (u32)__shfl((int)wbase, 0);
        if (pass) {
            u32 off = (u32)__popcll(mask & ((1ull << lane) - 1ull));
            alist[wbase + off] = (u32)tid;
            slist[wbase + off] = so;
        }
    }
    __syncthreads();
    int n = (int)nsh;
    u32 rep = (u32)(tid & 7);
#pragma unroll 4
    for (int i = tid; i < n * 20; i += 256) {
        int j = i / 20, k = i - j * 20;
        int a = m0 + (int)alist[j];
        float soj = slist[j];
        float4 v = cls4[a * 20 + k];
        float vv[4] = {v.x, v.y, v.z, v.w};
#pragma unroll
        for (int q = 0; q < 4; ++q) {
            float p = soj * sigm(vv[q]);
            u32 pb = __float_as_uint(p);
            if (pb >= PB_HALF) {
                u32 bin = min((pb >> 15) - 0x7E00u, 255u);
                atomicAdd(&h[rep * 257 + bin], 1u);
            }
        }
    }
    __syncthreads();
    if (tid < 256) {
        u32 s = 0;
        for (int r = 0; r < 8; ++r) s += h[r * 257 + tid];
        if (s) atomicAdd(&whist[L * 256 + tid], s);
    }
}

// ---- K2: filter — inline cutoff (suffix scan of hist), row-skip, emit candidates ----
__global__ __launch_bounds__(256) void filter_kernel(
    const float* __restrict__ o0, const float* __restrict__ c0,
    const float* __restrict__ o1, const float* __restrict__ c1,
    const float* __restrict__ o2, const float* __restrict__ c2,
    const u32* __restrict__ whist, u32* __restrict__ wcnt, u64* __restrict__ wcand) {
#pragma clang fp contract(off)
    __shared__ u32 sh[256];
    __shared__ u32 alist[128];
    __shared__ float slist[128];
    __shared__ int cutbin;
    __shared__ u32 thrsh, nsh;
    int tid = threadIdx.x;
    int b = (int)blockIdx.x;
    u32 lane = (u32)(tid & 63);
    int L, m0; block_map128(b, L, m0);
    const float* obj = (L == 0) ? o0 : ((L == 1) ? o1 : o2);
    const float* cls = (L == 0) ? c0 : ((L == 1) ? c1 : c2);
    const float4* cls4 = (const float4*)cls;
    if (tid == 0) { cutbin = -1; nsh = 0u; }
    sh[tid] = whist[L * 256 + tid];
    __syncthreads();
    for (int off = 1; off < 256; off <<= 1) {
        u32 v = (tid + off < 256) ? sh[tid + off] : 0u;
        __syncthreads();
        sh[tid] += v;
        __syncthreads();
    }
    if (sh[tid] >= 1000u) atomicMax(&cutbin, tid);
    __syncthreads();
    if (tid == 0) {
        // one-bin margin below the rank-1000 bin covers sqrt-tie hazards
        thrsh = (cutbin >= 0) ? (PB_HALF + ((u32)cutbin << 15)) - 0x8000u
                              : PB_QUARTER;
    }
    __syncthreads();
    u32 thr = thrsh;
    if (tid < 128) {
        float so = sigm(obj[m0 + tid]);
        bool pass = __float_as_uint(so) >= thr;  // p <= so
        u64 mask = __ballot(pass);
        u32 pc = (u32)__popcll(mask);
        u32 wbase = 0;
        if (lane == 0 && pc) wbase = atomicAdd(&nsh, pc);
        wbase = (u32)__shfl((int)wbase, 0);
        if (pass) {
            u32 off = (u32)__popcll(mask & ((1ull << lane) - 1ull));
            alist[wbase + off] = (u32)tid;
            slist[wbase + off] = so;
        }
    }
    __syncthreads();
    int n = (int)nsh;
#pragma unroll 4
    for (int i = tid; i < n * 20; i += 256) {
        int j = i / 20, k = i - j * 20;
        int a = m0 + (int)alist[j];
        float soj = slist[j];
        float4 v = cls4[a * 20 + k];
        float vv[4] = {v.x, v.y, v.z, v.w};
#pragma unroll
        for (int q = 0; q < 4; ++q) {
            float p = soj * sigm(vv[q]);
            u32 pb = __float_as_uint(p);
            bool emit = (pb >= thr);
            u64 em = __ballot(emit);  // active lanes are a tid-prefix of the wave
            if (em) {
                u32 cw = (u32)__popcll(em);
                u32 base = 0;
                if (lane == 0) base = atomicAdd(&wcnt[L], cw);  // 1 RMW per wave
                base = (u32)__shfl((int)base, 0);
                if (emit) {
                    u32 slot = base + (u32)__popcll(em & ((1ull << lane) - 1ull));
                    if (slot < CAND_CAP) {
                        float s = sqrtf(p);
                        u32 sb = __float_as_uint(s);
                        u32 idx = (u32)(a * NCLS + (k * 4 + q));
                        wcand[L * CAND_CAP + slot] = ((u64)(sb ^ 0xFFFFFFFFu) << 32) | idx;
                    }
                }
            }
        }
    }
}

// ---- K3a: exact top-1000 per level by rank-counting (keys unique) ----
__global__ __launch_bounds__(256) void rank_select_kernel(
    const u32* __restrict__ wcnt, const u64* __restrict__ wcand,
    u64* __restrict__ wsel) {
    __shared__ u64 s[CAND_CAP];
    int tid = threadIdx.x;
    int b = (int)blockIdx.x;
    int RL = b >> 4, part = b & 15;
    int n = (int)min(wcnt[RL], (u32)CAND_CAP);
    if (part * 256 >= n) return;
    for (int j = tid; j < n; j += 256) s[j] = wcand[RL * CAND_CAP + j];
    __syncthreads();
    int i = part * 256 + tid;
    if (i >= n) return;
    u64 mykey = s[i];
    int rank = 0;
#pragma unroll 4
    for (int j = 0; j < n; ++j) rank += (s[j] < mykey);  // uniform j: LDS broadcast
    if (rank < 1000) wsel[RL * 1000 + rank] = mykey;
}

// ---- K3b: merge + decode + per-class NMS (one block per class) ----
__global__ __launch_bounds__(256) void merge_nms_kernel(
    const u64* __restrict__ wsel,
    const float* __restrict__ r0, const float* __restrict__ r1,
    const float* __restrict__ r2, float* __restrict__ out) {
#pragma clang fp contract(off)
    __shared__ u64 smem64[4096];  // 32 KB
    int tid = threadIdx.x;
    int c = (int)blockIdx.x;  // class id
    u64* k = smem64;                        // [0..3000) keys
    u64* ckey = smem64 + 3000;              // [3000..3256) class keys
    u32* cidx = (u32*)(smem64 + 3256);      // 256 original idx
    u32* ncp = (u32*)(smem64 + 3384);
    if (tid == 0) *ncp = 0u;
    __syncthreads();
    for (int i = tid; i < NTOT; i += 256) {
        u64 S = wsel[i];
        u64 key = (S & 0xFFFFFFFF00000000ull) | (u32)i;
        k[i] = key;
        u32 idx = (u32)S;
        if ((int)(idx % NCLS) == c) {
            u32 p = atomicAdd(ncp, 1u);
            if (p < 256) { ckey[p] = key; cidx[p] = idx; }
        }
    }
    __syncthreads();
    int nc = (int)min(*ncp, 256u);
    int g = -1, r = 0;
    u32 myidx = 0;
    u64 mykey = 0;
    if (tid < nc) {
        mykey = ckey[tid];
        myidx = cidx[tid];
        for (int j = 0; j < nc; ++j) r += (ckey[j] < mykey);
        int t = (int)(u32)mykey;
        int ML = t / 1000;
        g = t - ML * 1000;
        for (int O = 0; O < 3; ++O) {
            if (O == ML) continue;
            int lo = 0, hi = 1000;
            while (lo < hi) {
                int mid = (lo + hi) >> 1;
                if (k[O * 1000 + mid] < mykey) lo = mid + 1; else hi = mid;
            }
            g += lo;
        }
    }
    __syncthreads();  // k[] no longer needed; reuse its space
    u32* garr = (u32*)smem64;              // 256
    u32* invp = (u32*)(smem64 + 64);       // 256
    float* bx = (float*)(smem64 + 512);    // 256*4 floats
    if (tid < nc) {
        garr[tid] = (u32)g;
        invp[r] = (u32)tid;
        int t = (int)(u32)mykey;
        int ML = t / 1000;
        u32 bits = (u32)(mykey >> 32) ^ 0xFFFFFFFFu;
        float score = __uint_as_float(bits);
        int m = (int)(myidx / NCLS);
        int w = (ML == 0) ? 320 : ((ML == 1) ? 160 : 80);
        float st = (ML == 0) ? 8.0f : ((ML == 1) ? 16.0f : 32.0f);
        const float* reg = (ML == 0) ? r0 : ((ML == 1) ? r1 : r2);
        int x = m % w, y = m / w;
        float rv0 = reg[m * 4 + 0], rv1 = reg[m * 4 + 1];
        float rv2 = reg[m * 4 + 2], rv3 = reg[m * 4 + 3];
        float ax = ((float)x + 0.5f) * st;
        float ay = ((float)y + 0.5f) * st;
        float cx = ax + rv0 * st;
        float cy = ay + rv1 * st;
        float bw = expf(rv2) * st;
        float bh = expf(rv3) * st;
        float hx = 0.5f * bw, hy = 0.5f * bh;
        float x1 = cx - hx, y1 = cy - hy, x2 = cx + hx, y2 = cy + hy;
        out[g * 4 + 0] = x1; out[g * 4 + 1] = y1;
        out[g * 4 + 2] = x2; out[g * 4 + 3] = y2;
        out[12000 + g] = score;
        out[15000 + g] = (float)c;
        float off = (float)c * 8192.0f;
        bx[tid * 4 + 0] = x1 + off; bx[tid * 4 + 1] = y1 + off;
        bx[tid * 4 + 2] = x2 + off; bx[tid * 4 + 3] = y2 + off;
    }
    __syncthreads();
    // greedy NMS in score order, 1 wave
    if (tid < 64) {
        int K = (nc + 63) >> 6;
        u32 alive = 0;
        for (int kk = 0; kk < K; ++kk) {
            int p = tid + (kk << 6);
            if (p < nc) {
                u32 bits = (u32)(ckey[invp[p]] >> 32) ^ 0xFFFFFFFFu;
                if (__uint_as_float(bits) > 0.05f) alive |= (1u << kk);
            }
        }
        for (int a = 0; a < nc; ++a) {
            u32 owner = (u32)__shfl((int)alive, a & 63);
            if ((owner >> (a >> 6)) & 1u) {
                int ra = (int)invp[a];
                float a0 = bx[ra * 4 + 0], a1 = bx[ra * 4 + 1];
                float a2 = bx[ra * 4 + 2], a3 = bx[ra * 4 + 3];
                float areaA = (a2 - a0) * (a3 - a1);
                for (int kk = (a >> 6); kk < K; ++kk) {
                    int p = tid + (kk << 6);
                    if (p > a && p < nc && ((alive >> kk) & 1u)) {
                        int rp = (int)invp[p];
                        float b0 = bx[rp * 4 + 0], b1 = bx[rp * 4 + 1];
                        float b2 = bx[rp * 4 + 2], b3 = bx[rp * 4 + 3];
                        float areaB = (b2 - b0) * (b3 - b1);
                        float ltx = fmaxf(a0, b0), lty = fmaxf(a1, b1);
                        float rbx = fminf(a2, b2), rby = fminf(a3, b3);
                        float wx = fmaxf(rbx - ltx, 0.0f), wy = fmaxf(rby - lty, 0.0f);
                        float inter = wx * wy;
                        float denom = ((areaA + areaB) - inter) + 1e-9f;
                        float iou = inter / denom;
                        if (iou > 0.6f) alive &= ~(1u << kk);
                    }
                }
            }
        }
        for (int kk = 0; kk < K; ++kk) {
            int p = tid + (kk << 6);
            if (p < nc)
                out[18000 + garr[invp[p]]] = ((alive >> kk) & 1u) ? 1.0f : 0.0f;
        }
    }
}

extern "C" void kernel_launch(void* const* d_in, const int* in_sizes, int n_in,
                              void* d_out, int out_size, void* d_ws, size_t ws_size,
                              hipStream_t stream) {
    const float* obj0 = (const float*)d_in[0];
    const float* cls0 = (const float*)d_in[1];
    const float* reg0 = (const float*)d_in[2];
    const float* obj1 = (const float*)d_in[3];
    const float* cls1 = (const float*)d_in[4];
    const float* reg1 = (const float*)d_in[5];
    const float* obj2 = (const float*)d_in[6];
    const float* cls2 = (const float*)d_in[7];
    const float* reg2 = (const float*)d_in[8];
    float* out = (float*)d_out;
    char* ws = (char*)d_ws;

    u32* hist = (u32*)(ws + WS_HIST);
    u32* cnt  = (u32*)(ws + WS_CNT);
    u64* cand = (u64*)(ws + WS_CAND);
    u64* sel  = (u64*)(ws + WS_SEL);

    hipMemsetAsync(ws, 0, 4096, stream);  // hist + cnt
    hist_kernel<<<1050, 256, 0, stream>>>(obj0, cls0, obj1, cls1, obj2, cls2, hist);
    filter_kernel<<<1050, 256, 0, stream>>>(obj0, cls0, obj1, cls1, obj2, cls2,
                                            hist, cnt, cand);
    rank_select_kernel<<<48, 256, 0, stream>>>(cnt, cand, sel);
    merge_nms_kernel<<<80, 256, 0, stream>>>(sel, reg0, reg1, reg2, out);
}